// Round 1
// baseline (946.051 us; speedup 1.0000x reference)
//
#include <hip/hip_runtime.h>
#include <math.h>

// Problem constants
#define BATCH      16384
#define EMB        64
#define NSP        26
#define NCH        28          // 2 dense + 26 sparse k-chunks of 64
#define HID        128
#define MT         64          // samples per block
#define LDA        72          // padded leading dim in bf16 elems (144 B: breaks 32-bank aliasing)
#define CHUNK_SHORTS (HID * LDA)      // 9216 shorts = 18432 B per W1 k-chunk
#define CHUNK_BYTES  (CHUNK_SHORTS * 2)

typedef __attribute__((ext_vector_type(8))) short  short8;
typedef __attribute__((ext_vector_type(4))) float  float4v;

__device__ __forceinline__ unsigned short f2bf(float x) {
    unsigned u = __builtin_bit_cast(unsigned, x);
    u += 0x7FFFu + ((u >> 16) & 1u);   // round-to-nearest-even
    return (unsigned short)(u >> 16);
}

// ---------------------------------------------------------------------------
// Prep: W1[k=1792][n=128] fp32  ->  28 chunks of Bt[n=128][k=64] bf16,
// row stride LDA=72 (pad garbage, never read by MFMA frags), linear layout so
// the main kernel can global_load_lds it verbatim.
// ---------------------------------------------------------------------------
__global__ __launch_bounds__(256) void prep_w1(const float* __restrict__ W1,
                                               unsigned short* __restrict__ wt) {
    __shared__ float tile[64][129];    // +1 pad: conflict-free column reads
    const int t   = blockIdx.x;        // k-chunk
    const int tid = threadIdx.x;

    for (int i = tid; i < 64 * 128; i += 256) {
        int k = i >> 7, n = i & 127;                 // coalesced global read
        tile[k][n] = W1[(t * 64 + k) * 128 + n];
    }
    __syncthreads();

    unsigned short* dst = wt + t * CHUNK_SHORTS;
    for (int i = tid; i < 128 * 64; i += 256) {
        int n = i >> 6, j = i & 63;                  // contiguous 2B writes per row
        dst[n * LDA + j] = f2bf(tile[j][n]);
    }
}

// ---------------------------------------------------------------------------
// Fused gather + MLP.  Block = 256 thr (4 waves), 64 samples/block.
// Wave w computes rows [w*16, w*16+16) x all 128 cols via 8 16x16x32 acc tiles.
// ---------------------------------------------------------------------------
__global__ __launch_bounds__(256) void dlrm_fused(
        const int*   __restrict__ uids,
        const int*   __restrict__ iids,
        const int*   __restrict__ sidx,
        const float* __restrict__ uemb,
        const float* __restrict__ iemb,
        const float* __restrict__ stab,
        const unsigned short* __restrict__ wt,
        const float* __restrict__ b1,
        const float* __restrict__ W2,
        const float* __restrict__ b2p,
        float*       __restrict__ out) {

    __shared__ __align__(16) unsigned short A_lds[MT * LDA];        //  9216 B
    __shared__ __align__(16) unsigned short Bt_lds[CHUNK_SHORTS];   // 18432 B
    __shared__ int offs[NCH][MT];                                   //  7168 B

    const int tid  = threadIdx.x;
    const int s0   = blockIdx.x * MT;
    const int lane = tid & 63;
    const int wv   = tid >> 6;
    const int q    = lane >> 4;
    const int n0   = lane & 15;

    // ---- index prefill: element offsets into each table -------------------
    for (int i = tid; i < NCH * MT; i += 256) {
        int t = i >> 6, s = i & 63;
        int g = s0 + s;
        int off;
        if (t == 0)      off = uids[g] * EMB;
        else if (t == 1) off = iids[g] * EMB;
        else {
            int f = t - 2;
            off = (f * 100000 + sidx[g * NSP + f]) * EMB;
        }
        offs[t][s] = off;
    }

    // ---- epilogue constants (L2-resident) ---------------------------------
    float b1r[8], w2r[8];
#pragma unroll
    for (int nt = 0; nt < 8; nt++) {
        b1r[nt] = b1[nt * 16 + n0];
        w2r[nt] = W2[nt * 16 + n0];
    }
    const float bias2 = b2p[0];

    float4v acc[8];
#pragma unroll
    for (int i = 0; i < 8; i++) acc[i] = (float4v){0.f, 0.f, 0.f, 0.f};

    __syncthreads();   // offs visible

    const int sA = tid >> 2;   // sample this thread stages (0..63)
    const int pA = tid & 3;    // which 16-float segment of the 64-float row

    for (int t = 0; t < NCH; t++) {
        // ---- stage W1 chunk: async global->LDS, 16B/lane, linear layout ----
        const char* gB = (const char*)wt + (size_t)t * CHUNK_BYTES;
        for (int ri = wv; ri < CHUNK_BYTES / 1024; ri += 4) {
            __builtin_amdgcn_global_load_lds(
                (const __attribute__((address_space(1))) unsigned int*)
                    (gB + ri * 1024 + lane * 16),
                (__attribute__((address_space(3))) unsigned int*)
                    ((char*)Bt_lds + ri * 1024),
                16, 0, 0);
        }

        // ---- stage gathered A rows: 4 thr/row, float4 x4, cvt->bf16 -------
        const float* base = (t == 0) ? uemb : (t == 1) ? iemb : stab;
        const float* row  = base + offs[t][sA];
        float4v r0 = *(const float4v*)(row + pA * 16 + 0);
        float4v r1 = *(const float4v*)(row + pA * 16 + 4);
        float4v r2 = *(const float4v*)(row + pA * 16 + 8);
        float4v r3 = *(const float4v*)(row + pA * 16 + 12);

        unsigned short cv[16];
#pragma unroll
        for (int j = 0; j < 4; j++) {
            cv[j]      = f2bf(r0[j]);
            cv[4 + j]  = f2bf(r1[j]);
            cv[8 + j]  = f2bf(r2[j]);
            cv[12 + j] = f2bf(r3[j]);
        }
        *(short8*)&A_lds[sA * LDA + pA * 16 + 0] = *(short8*)&cv[0];
        *(short8*)&A_lds[sA * LDA + pA * 16 + 8] = *(short8*)&cv[8];

        __syncthreads();   // drains vmcnt (global_load_lds) + lgkmcnt

        // ---- MFMA: 2 k-steps x 8 n-tiles ----------------------------------
#pragma unroll
        for (int ks = 0; ks < 2; ks++) {
            short8 a = *(const short8*)&A_lds[(wv * 16 + n0) * LDA + ks * 32 + q * 8];
#pragma unroll
            for (int nt = 0; nt < 8; nt++) {
                short8 b = *(const short8*)&Bt_lds[(nt * 16 + n0) * LDA + ks * 32 + q * 8];
                acc[nt] = __builtin_amdgcn_mfma_f32_16x16x32_bf16(a, b, acc[nt], 0, 0, 0);
            }
        }
        __syncthreads();   // before next tile overwrites LDS
    }

    // ---- epilogue: bias + ReLU + W2 dot + sigmoid -------------------------
    // C/D layout: col = n0, row = q*4 + r  (verified m89/m91)
#pragma unroll
    for (int r = 0; r < 4; r++) {
        float v = 0.f;
#pragma unroll
        for (int nt = 0; nt < 8; nt++) {
            float h = acc[nt][r] + b1r[nt];
            h = h > 0.f ? h : 0.f;
            v += h * w2r[nt];
        }
        v += __shfl_xor(v, 1);
        v += __shfl_xor(v, 2);
        v += __shfl_xor(v, 4);
        v += __shfl_xor(v, 8);
        if (n0 == 0) {
            float raw = v + bias2;
            out[s0 + wv * 16 + q * 4 + r] = 1.f / (1.f + expf(-raw));
        }
    }
}

// ---------------------------------------------------------------------------
extern "C" void kernel_launch(void* const* d_in, const int* in_sizes, int n_in,
                              void* d_out, int out_size, void* d_ws, size_t ws_size,
                              hipStream_t stream) {
    const int*   uids = (const int*)  d_in[0];
    const int*   iids = (const int*)  d_in[1];
    const int*   sidx = (const int*)  d_in[2];
    const float* uemb = (const float*)d_in[3];
    const float* iemb = (const float*)d_in[4];
    const float* stab = (const float*)d_in[5];
    const float* W1   = (const float*)d_in[6];
    const float* b1   = (const float*)d_in[7];
    const float* W2   = (const float*)d_in[8];
    const float* b2   = (const float*)d_in[9];
    float* out = (float*)d_out;
    unsigned short* wt = (unsigned short*)d_ws;   // needs 28*9216*2 = 516096 B

    prep_w1<<<NCH, 256, 0, stream>>>(W1, wt);
    dlrm_fused<<<BATCH / MT, 256, 0, stream>>>(uids, iids, sidx, uemb, iemb, stab,
                                               wt, b1, W2, b2, out);
}